// Round 1
// baseline (1071.418 us; speedup 1.0000x reference)
//
#include <hip/hip_runtime.h>

#define NN 100000
#define EE 1600000
#define QQ 64
#define HH 64
#define DTc 0.1f
#define REGc 1e-6f
#define WQc (1.0f / 64.0f)

// ---------------------------------------------------------------------------
// deg[i] = number of edges with src == i (float, exact for counts < 2^24)
// ---------------------------------------------------------------------------
__global__ __launch_bounds__(256) void deg_kernel(const int* __restrict__ esrc,
                                                  float* __restrict__ deg) {
    int i = blockIdx.x * 256 + threadIdx.x;
    if (i < EE) unsafeAtomicAdd(&deg[esrc[i]], 1.0f);
}

// ---------------------------------------------------------------------------
// One wave (64 lanes) per edge; lane = velocity bin q.
// msg = (w_e/deg[src]) * xi[q] * (f+[dst] - f+[src])
// trans[src] += msg ; trans[dst] -= msg   (trans = outflow - inflow)
// ---------------------------------------------------------------------------
__global__ __launch_bounds__(256) void edge_kernel(
    const float* __restrict__ f, const int* __restrict__ esrc,
    const int* __restrict__ edst, const float* __restrict__ ew,
    const float* __restrict__ deg, const float* __restrict__ xi,
    float* __restrict__ trans) {
    int tid  = threadIdx.x;
    int lane = tid & 63;
    int e    = blockIdx.x * 4 + (tid >> 6);   // grid sized exactly: EE/4 blocks
    int s = esrc[e];
    int d = edst[e];
    float qe = ew[e] / deg[s];
    float xv = xi[lane];
    float fs = fmaxf(f[s * 64 + lane], 0.f);
    float fd = fmaxf(f[d * 64 + lane], 0.f);
    float m = qe * xv * (fd - fs);
    unsafeAtomicAdd(&trans[s * 64 + lane],  m);
    unsafeAtomicAdd(&trans[d * 64 + lane], -m);
}

// ---------------------------------------------------------------------------
// Per-node: clamp f -> 5-layer MLP (relu x4, tanh) -> collision-invariance
// projection (analytic 2x2) -> fused final update with transport+source+relu.
// Block = 128 nodes, one thread per node. Activations in VGPRs, weights via
// uniform scalar loads, layer bounce through padded (stride 65) LDS rows.
// ---------------------------------------------------------------------------
__global__ __launch_bounds__(128) void node_kernel(
    const float* __restrict__ f, const float* __restrict__ macro_u,
    const float* __restrict__ source, const float* __restrict__ xi,
    const float* __restrict__ w_in, const float* __restrict__ b_in,
    const float* __restrict__ w_hid, const float* __restrict__ b_hid,
    const float* __restrict__ w_out, const float* __restrict__ b_out,
    const float* __restrict__ trans, float* __restrict__ out) {
    __shared__ float sbuf[128 * 65];   // 33.3 KB: per-thread padded rows
    __shared__ float s0s[128], s1s[128], us[128];

    const int t = threadIdx.x;
    const int nodeBase = blockIdx.x * 128;
    const int gbase = nodeBase * 64;
    const int total = NN * 64;

    // ---- stage clamped f tile, coalesced global -> padded LDS ----
    for (int i = 0; i < 64; i++) {
        int l = i * 128 + t;
        int g = gbase + l;
        float v = 0.f;
        if (g < total) v = fmaxf(f[g], 0.f);
        sbuf[(l >> 6) * 65 + (l & 63)] = v;
    }
    __syncthreads();

    const int n = nodeBase + t;
    const bool valid = (n < NN);
    const float u = valid ? macro_u[n] : 0.f;

    float* myrow = &sbuf[t * 65];
    float x[64];
#pragma unroll
    for (int q = 0; q < 64; q++) x[q] = myrow[q];

    float v0 = 0.f, v1 = 0.f, sxs = 0.f, sxs2 = 0.f;

    for (int layer = 0; layer < 5; layer++) {
        const float* W;
        const float* B;
        if (layer == 0)      { W = w_in;                        B = b_in; }
        else if (layer < 4)  { W = w_hid + (layer - 1) * 4096;  B = b_hid + (layer - 1) * 64; }
        else                 { W = w_out;                       B = b_out; }
        const bool last = (layer == 4);

        for (int h = 0; h < 64; h += 8) {
            float a[8];
#pragma unroll
            for (int j = 0; j < 8; j++) a[j] = B[h + j];
#pragma unroll
            for (int q = 0; q < 64; q++) {
                float xv = x[q];
                const float* wr = W + q * 64 + h;
#pragma unroll
                for (int j = 0; j < 8; j++) a[j] = fmaf(xv, wr[j], a[j]);
            }
            if (!last) {
#pragma unroll
                for (int j = 0; j < 8; j++) myrow[h + j] = fmaxf(a[j], 0.f);
            } else {
#pragma unroll
                for (int j = 0; j < 8; j++) {
                    float om = tanhf(a[j]);
                    float xs = xi[h + j] + u;
                    v0 += WQc * om;
                    v1 += WQc * xs * om;
                    sxs += xs;
                    sxs2 += xs * xs;
                    myrow[h + j] = om;   // omega stays in LDS for output sweep
                }
            }
        }
        if (layer < 4) {
#pragma unroll
            for (int q = 0; q < 64; q++) x[q] = myrow[q];
        }
    }

    // ---- analytic CCT (2x2) + Cramer solve ----
    // c00 = sum w^2 = 1/64 ; c01 = w^2 * sum(xs) ; c11 = w^2 * sum(xs^2)
    float c00 = WQc + REGc;
    float c01 = WQc * WQc * sxs;
    float c11 = WQc * WQc * sxs2 + REGc;
    float det = c00 * c11 - c01 * c01;
    float inv = 1.0f / det;
    float sv0 = (c11 * v0 - c01 * v1) * inv;
    float sv1 = (c00 * v1 - c01 * v0) * inv;
    s0s[t] = sv0;
    s1s[t] = sv1;
    us[t] = u;
    __syncthreads();

    // ---- coalesced output sweep: omega* + transport + source, final relu ----
    const float xiq = xi[t & 63];   // q = (i*128+t)&63 == t&63 for all i
    for (int i = 0; i < 64; i++) {
        int l = i * 128 + t;
        int g = gbase + l;
        if (g < total) {
            int nl = l >> 6;
            float om = sbuf[nl * 65 + (l & 63)];
            float xs = xiq + us[nl];
            float omst = om - WQc * (s0s[nl] + xs * s1s[nl]);
            float val = fmaxf(f[g], 0.f) + DTc * (source[g] + omst - trans[g]);
            out[g] = fmaxf(val, 0.f);
        }
    }
}

extern "C" void kernel_launch(void* const* d_in, const int* in_sizes, int n_in,
                              void* d_out, int out_size, void* d_ws, size_t ws_size,
                              hipStream_t stream) {
    const float* f       = (const float*)d_in[0];
    const float* macro_u = (const float*)d_in[1];
    const float* source  = (const float*)d_in[2];
    const int*   esrc    = (const int*)d_in[3];
    const int*   edst    = (const int*)d_in[4];
    const float* ew      = (const float*)d_in[5];
    const float* xi      = (const float*)d_in[6];
    const float* w_in    = (const float*)d_in[7];
    const float* b_in    = (const float*)d_in[8];
    const float* w_hid   = (const float*)d_in[9];
    const float* b_hid   = (const float*)d_in[10];
    const float* w_out   = (const float*)d_in[11];
    const float* b_out   = (const float*)d_in[12];
    float* out = (float*)d_out;

    float* deg   = (float*)d_ws;        // NN floats
    float* trans = deg + NN;            // NN*64 floats

    hipMemsetAsync(d_ws, 0, (size_t)(NN + NN * 64) * sizeof(float), stream);
    deg_kernel<<<(EE + 255) / 256, 256, 0, stream>>>(esrc, deg);
    edge_kernel<<<EE / 4, 256, 0, stream>>>(f, esrc, edst, ew, deg, xi, trans);
    node_kernel<<<(NN + 127) / 128, 128, 0, stream>>>(
        f, macro_u, source, xi, w_in, b_in, w_hid, b_hid, w_out, b_out, trans, out);
}